// Round 1
// baseline (44.769 us; speedup 1.0000x reference)
//
#include <hip/hip_runtime.h>
#include <math.h>

#define NUM_RADIAL 8
#define EMB_DIM    64
#define N_ELEM     83
#define TILE       256

// ---------------------------------------------------------------------------
// Kernel 1: t_table[z][k] = emb_table[z] . dense_w[:,k] + dense_b[k]
// 83 x 8 = 664 outputs; trivial.
// ---------------------------------------------------------------------------
__global__ void srb_precompute_t(const float* __restrict__ emb,
                                 const float* __restrict__ dw,
                                 const float* __restrict__ db,
                                 float* __restrict__ t_table) {
    int idx = blockIdx.x * blockDim.x + threadIdx.x;
    if (idx >= N_ELEM * NUM_RADIAL) return;
    int z = idx >> 3;
    int k = idx & 7;
    float acc = db[k];
    const float* e = emb + z * EMB_DIM;
    #pragma unroll 8
    for (int j = 0; j < EMB_DIM; ++j)
        acc += e[j] * dw[j * NUM_RADIAL + k];
    t_table[idx] = acc;
}

// ---------------------------------------------------------------------------
// Kernel 2: main edge kernel.
// Phase 1: thread i computes edge (blk*256+i): Y[16] and g[4][8] into LDS.
//          g[l][k] = t[k]*rb[k]*w[l][k]*gate[k], gate[k]=sigmoid(t*rb*w[0][k])
// Phase 2: block writes its 256-edge output tile (8192 float4) with
//          consecutive lanes -> consecutive float4 (fully coalesced).
//          out[e][lm][k] = Y[lm] * g[deg(lm)][k]
// ---------------------------------------------------------------------------
__global__ __launch_bounds__(256) void srb_main(
    const float* __restrict__ disp,
    const int*   __restrict__ Zj,
    const float* __restrict__ tw,       // tensor_w, 4 x 8
    const float* __restrict__ t_table,  // 83 x 8
    float*       __restrict__ out,
    int n_edges)
{
    __shared__ float Yl[TILE * 17];   // stride 17 (odd) -> conflict-free b32
    __shared__ float Gl[TILE * 33];   // stride 33 (odd) -> conflict-free b32

    const int tid = threadIdx.x;
    const int e   = blockIdx.x * TILE + tid;

    // uniform tensor_w -> scalar loads
    float w[4][NUM_RADIAL];
    #pragma unroll
    for (int l = 0; l < 4; ++l)
        #pragma unroll
        for (int k = 0; k < NUM_RADIAL; ++k)
            w[l][k] = tw[l * NUM_RADIAL + k];

    if (e < n_edges) {
        const float dx = disp[3 * e + 0];
        const float dy = disp[3 * e + 1];
        const float dz = disp[3 * e + 2];
        const float r2 = dx * dx + dy * dy + dz * dz;
        const float r  = sqrtf(r2);
        const float rinv = (r > 0.0f) ? (1.0f / r) : 0.0f;
        const float x = dx * rinv, y = dy * rinv, z = dz * rinv;
        const float x2 = x * x, y2 = y * y, z2 = z * z;

        const float s3   = 1.7320508075688772f;   // sqrt(3)
        const float s15  = 3.8729833462074170f;   // sqrt(15)
        const float s5_8 = 0.7905694150420949f;   // sqrt(5/8)
        const float s3_8 = 0.6123724356957945f;   // sqrt(3/8)

        float* Yp = &Yl[tid * 17];
        Yp[0]  = 1.0f;
        Yp[1]  = x;
        Yp[2]  = y;
        Yp[3]  = z;
        Yp[4]  = s3 * x * y;
        Yp[5]  = s3 * y * z;
        Yp[6]  = 0.5f * (3.0f * z2 - 1.0f);
        Yp[7]  = s3 * x * z;
        Yp[8]  = 0.5f * s3 * (x2 - y2);
        Yp[9]  = s5_8 * y * (3.0f * x2 - y2);
        Yp[10] = s15 * x * y * z;
        Yp[11] = s3_8 * y * (5.0f * z2 - 1.0f);
        Yp[12] = 0.5f * z * (5.0f * z2 - 3.0f);
        Yp[13] = s3_8 * x * (5.0f * z2 - 1.0f);
        Yp[14] = 0.5f * s15 * z * (x2 - y2);
        Yp[15] = s5_8 * x * (x2 - 3.0f * y2);

        const float PI = 3.14159265358979323846f;
        const float cut = (r < 5.0f) ? (0.5f * (cosf(PI * r * 0.2f) + 1.0f))
                                     : 0.0f;
        const float pib = PI * r * 0.2f;   // pi*r/CUTOFF

        // t[k] gather (two aligned float4 loads from the 83x8 table)
        const int zidx = Zj[e];
        const float4 t0 = reinterpret_cast<const float4*>(t_table)[zidx * 2 + 0];
        const float4 t1 = reinterpret_cast<const float4*>(t_table)[zidx * 2 + 1];
        float t[NUM_RADIAL] = { t0.x, t0.y, t0.z, t0.w, t1.x, t1.y, t1.z, t1.w };

        float* Gp = &Gl[tid * 33];
        #pragma unroll
        for (int k = 0; k < NUM_RADIAL; ++k) {
            const float px = pib * (float)(k + 1);
            const float s  = (px != 0.0f) ? (sinf(px) / px) : 1.0f;  // sinc
            const float rb = s * cut;
            const float c  = t[k] * rb;
            const float y0 = c * w[0][k];
            const float gate = 1.0f / (1.0f + expf(-y0));
            const float cg = c * gate;
            Gp[0  + k] = cg * w[0][k];
            Gp[8  + k] = cg * w[1][k];
            Gp[16 + k] = cg * w[2][k];
            Gp[24 + k] = cg * w[3][k];
        }
    }

    __syncthreads();

    // Phase 2: coalesced output write
    const int totalF4 = n_edges * 32;                 // 12.8M, fits in int
    const int baseF4  = blockIdx.x * (TILE * 32);
    float4* out4 = reinterpret_cast<float4*>(out);
    #pragma unroll
    for (int it = 0; it < 32; ++it) {
        const int lf = it * 256 + tid;                // [0, 8192)
        const int f  = baseF4 + lf;
        if (f < totalF4) {
            const int el = lf >> 5;                   // local edge
            const int j  = lf & 31;                   // float4 within edge
            const int lm = j >> 1;
            const int k0 = (j & 1) * 4;
            const int l  = (lm > 0) + (lm > 3) + (lm > 8);
            const float yv = Yl[el * 17 + lm];
            const int gb = el * 33 + l * 8 + k0;
            float4 o;
            o.x = yv * Gl[gb + 0];
            o.y = yv * Gl[gb + 1];
            o.z = yv * Gl[gb + 2];
            o.w = yv * Gl[gb + 3];
            out4[f] = o;
        }
    }
}

extern "C" void kernel_launch(void* const* d_in, const int* in_sizes, int n_in,
                              void* d_out, int out_size, void* d_ws, size_t ws_size,
                              hipStream_t stream) {
    const float* disp = (const float*)d_in[0];
    const int*   Zj   = (const int*)  d_in[1];
    const float* emb  = (const float*)d_in[2];
    const float* dw   = (const float*)d_in[3];
    const float* db   = (const float*)d_in[4];
    const float* tw   = (const float*)d_in[5];
    float* t_table = (float*)d_ws;                    // 83*8 floats = 2656 B
    float* out     = (float*)d_out;

    const int n = in_sizes[1];                        // N_EDGES

    hipLaunchKernelGGL(srb_precompute_t, dim3(3), dim3(256), 0, stream,
                       emb, dw, db, t_table);

    const int nblocks = (n + TILE - 1) / TILE;
    hipLaunchKernelGGL(srb_main, dim3(nblocks), dim3(256), 0, stream,
                       disp, Zj, tw, t_table, out, n);
}